// Round 18
// baseline (562.473 us; speedup 1.0000x reference)
//
#include <hip/hip_runtime.h>
#include <hip/hip_fp16.h>
#include <math.h>

#define BATCH   8
#define LSEQ    197
#define LPAD    200                // LSEQ padded to multiple of 8 for scan batches
#define NPATCH  196
#define NPTOK   (BATCH * NPATCH)   // 1568
#define NTOK    (BATCH * LSEQ)     // 1576
#define MPAD    1664               // padded row count for f16 act arrays (>= 25*64)
#define DMODEL  512
#define DINNER  1024
#define NSTATE  16
#define DRANK   32
#define NLAYER  8
#define NCLS    1000
#define PDIM    3840               // 16*16*15

typedef _Float16 f16x8 __attribute__((ext_vector_type(8)));
typedef float    f32x4 __attribute__((ext_vector_type(4)));
typedef unsigned short us8 __attribute__((ext_vector_type(8)));

// Fast transcendentals (v_exp/v_log/v_rcp based; ~1e-7 rel err vs 0.0156 absmax)
__device__ __forceinline__ float f_rcp(float x) { return __builtin_amdgcn_rcpf(x); }
__device__ __forceinline__ float sp_silu(float x) { return x * f_rcp(1.0f + __expf(-x)); }
__device__ __forceinline__ float sp_softplus(float x) {
    return x > 20.0f ? x : __logf(1.0f + __expf(x));
}

template <int N>
__device__ __forceinline__ void vm_wait() {
    if constexpr (N == 0)       asm volatile("s_waitcnt vmcnt(0)" ::: "memory");
    else if constexpr (N == 4)  asm volatile("s_waitcnt vmcnt(4)" ::: "memory");
    else if constexpr (N == 6)  asm volatile("s_waitcnt vmcnt(6)" ::: "memory");
    else if constexpr (N == 8)  asm volatile("s_waitcnt vmcnt(8)" ::: "memory");
    else if constexpr (N == 12) asm volatile("s_waitcnt vmcnt(12)" ::: "memory");
}

// N interleaved 16-lane row sums (row_shr DPP tree); lane 15 of each row gets
// the sum. dpp_ctrl must be a literal constant -> explicit 4-step expansion.
#define DPP_ROW_SHR_STEP(P, NB, CTRL)                                          \
    {                                                                          \
        float t_[NB];                                                          \
        _Pragma("unroll")                                                      \
        for (int i_ = 0; i_ < NB; ++i_)                                        \
            t_[i_] = __int_as_float(__builtin_amdgcn_update_dpp(               \
                0, __float_as_int(P[i_]), CTRL, 0xF, 0xF, true));              \
        _Pragma("unroll")                                                      \
        for (int i_ = 0; i_ < NB; ++i_) P[i_] += t_[i_];                       \
    }

template <int NB>
__device__ __forceinline__ void row_sum16v(float* p) {
    DPP_ROW_SHR_STEP(p, NB, 0x111);   // row_shr:1
    DPP_ROW_SHR_STEP(p, NB, 0x112);   // row_shr:2
    DPP_ROW_SHR_STEP(p, NB, 0x114);   // row_shr:4
    DPP_ROW_SHR_STEP(p, NB, 0x118);   // row_shr:8
}

// Store f16 value at swizzled position (row, k) of a [*][K] f16 array.
// Swizzle: byte-in-row ^= (row&7)<<4  (permutes 16B blocks within 128B chunks).
__device__ __forceinline__ void store_f16(char* __restrict__ Hb,
                                          int row, int k, int K, float v) {
    size_t byte = (size_t)row * (size_t)(K * 2) +
                  (size_t)(((unsigned)(k * 2)) ^ (unsigned)((row & 7) << 4));
    *(__half*)(Hb + byte) = __float2half_rn(v);
}

// 4 consecutive k (k4 multiple of 4): one 8B store (stays inside a 16B block).
__device__ __forceinline__ void store_f16x4(char* __restrict__ Hb,
                                            int row, int k4, int K, float4 v) {
    size_t byte = (size_t)row * (size_t)(K * 2) +
                  (size_t)(((unsigned)(k4 * 2)) ^ (unsigned)((row & 7) << 4));
    *(ushort4*)(Hb + byte) = make_ushort4(
        __half_as_ushort(__float2half_rn(v.x)), __half_as_ushort(__float2half_rn(v.y)),
        __half_as_ushort(__float2half_rn(v.z)), __half_as_ushort(__float2half_rn(v.w)));
}

// 256-thread block reduction of two values; lds must be 8 floats.
__device__ __forceinline__ float2 block_reduce2(float a, float b, float* lds) {
#pragma unroll
    for (int off = 32; off > 0; off >>= 1) {
        a += __shfl_down(a, off);
        b += __shfl_down(b, off);
    }
    int lane = threadIdx.x & 63, w = threadIdx.x >> 6;
    if (lane == 0) { lds[w] = a; lds[4 + w] = b; }
    __syncthreads();
    float sa = lds[0] + lds[1] + lds[2] + lds[3];
    float sb = lds[4] + lds[5] + lds[6] + lds[7];
    return make_float2(sa, sb);
}

// Wave-level reduction of two values across 64 lanes (butterfly).
__device__ __forceinline__ float2 wave_reduce2(float a, float b) {
#pragma unroll
    for (int off = 32; off > 0; off >>= 1) {
        a += __shfl_xor(a, off);
        b += __shfl_xor(b, off);
    }
    return make_float2(a, b);
}

// ---------------------------------------------------------------- patch stage
__global__ __launch_bounds__(256) void k_patch_ln(
    const float* __restrict__ img, const float* __restrict__ lnw,
    const float* __restrict__ lnb, char* __restrict__ Xph) {
    __shared__ float vals[PDIM];
    __shared__ float red[8];
    int tok = blockIdx.x;
    int b = tok / NPATCH, p = tok % NPATCH;
    int gy = p / 14, gx = p % 14;
    int tid = threadIdx.x;
    int py = tid >> 4, px = tid & 15;
    int h0 = gy * 16 + py, w0 = gx * 16 + px;
    const int dh[5] = {0, 0, 0, -1, 1};
    const int dw[5] = {0, -1, 1, 0, 0};
    float s = 0.f, ss = 0.f;
#pragma unroll
    for (int c = 0; c < 15; ++c) {
        int g = c / 3, ch = c % 3;
        int h = h0 + dh[g], w = w0 + dw[g];
        float v = 0.f;
        if ((unsigned)h < 224u && (unsigned)w < 224u)
            v = img[((b * 3 + ch) * 224 + h) * 224 + w];
        vals[tid * 15 + c] = v;
        s += v; ss += v * v;
    }
    float2 t2 = block_reduce2(s, ss, red);
    float mean = t2.x * (1.0f / PDIM);
    float var  = t2.y * (1.0f / PDIM) - mean * mean;
    float rstd = 1.0f / sqrtf(var + 1e-5f);
    for (int j = 0; j < 15; ++j) {
        int e = tid + j * 256;
        float v = (vals[e] - mean) * rstd * lnw[e] + lnb[e];
        store_f16(Xph, tok, e, PDIM, v);
    }
}

// ------------------- token LN, wave-per-token (4 tokens per 256-thr block)
__global__ __launch_bounds__(256) void k_ln(
    const float* __restrict__ x, const float* __restrict__ w,
    const float* __restrict__ b, char* __restrict__ yh) {
    int wv = threadIdx.x >> 6, lane = threadIdx.x & 63;
    int t = blockIdx.x * 4 + wv;
    if (t >= NTOK) return;
    const float* xr = x + (size_t)t * DMODEL;
    float v[8];
    float s = 0.f, ss = 0.f;
#pragma unroll
    for (int j = 0; j < 8; ++j) {
        v[j] = xr[lane + j * 64];
        s += v[j]; ss += v[j] * v[j];
    }
    float2 t2 = wave_reduce2(s, ss);
    float mean = t2.x * (1.0f / DMODEL);
    float var  = t2.y * (1.0f / DMODEL) - mean * mean;
    float rstd = 1.0f / sqrtf(var + 1e-5f);
#pragma unroll
    for (int j = 0; j < 8; ++j) {
        int e = lane + j * 64;
        store_f16(yh, t, e, DMODEL, (v[j] - mean) * rstd * w[e] + b[e]);
    }
}

// --- fused: xtok += sum(part[0..1]); yln = LN(xtok). Wave-per-token.
__global__ __launch_bounds__(256) void k_red_ln(
    const float* __restrict__ part, float* __restrict__ xtok,
    const float* __restrict__ w, const float* __restrict__ b,
    char* __restrict__ yh) {
    int wv = threadIdx.x >> 6, lane = threadIdx.x & 63;
    int t = blockIdx.x * 4 + wv;
    if (t >= NTOK) return;
    size_t base = (size_t)t * DMODEL;
    float v[8];
    float s = 0.f, ss = 0.f;
#pragma unroll
    for (int j = 0; j < 8; ++j) {
        int e = lane + j * 64;
        float vv = xtok[base + e];
#pragma unroll
        for (int k = 0; k < 2; ++k)
            vv += part[(size_t)k * (NTOK * DMODEL) + base + e];
        xtok[base + e] = vv;
        v[j] = vv;
        s += vv; ss += vv * vv;
    }
    float2 t2 = wave_reduce2(s, ss);
    float mean = t2.x * (1.0f / DMODEL);
    float var  = t2.y * (1.0f / DMODEL) - mean * mean;
    float rstd = 1.0f / sqrtf(var + 1e-5f);
#pragma unroll
    for (int j = 0; j < 8; ++j) {
        int e = lane + j * 64;
        store_f16(yh, t, e, DMODEL, (v[j] - mean) * rstd * w[e] + b[e]);
    }
}

// --------------------------------------------- weight transpose + f16 cast
__global__ __launch_bounds__(256) void k_wT(
    const float* __restrict__ W, char* __restrict__ Th,
    int Ks, int Ns, size_t wStride, size_t tByteStride) {
    __shared__ float t[32][33];
    int z = blockIdx.z;
    const float* Wz = W + (size_t)z * wStride;
    char* ThZ = Th + (size_t)z * tByteStride;
    int n0 = blockIdx.x * 32, k0 = blockIdx.y * 32;
    int tx = threadIdx.x, ty = threadIdx.y;
#pragma unroll
    for (int r = 0; r < 4; ++r) {
        int k = k0 + ty + r * 8, n = n0 + tx;
        t[tx][ty + r * 8] = (n < Ns) ? Wz[(size_t)k * Ns + n] : 0.f;
    }
    __syncthreads();
#pragma unroll
    for (int r = 0; r < 4; ++r) {
        int n = n0 + ty + r * 8, k = k0 + tx;
        float v = t[ty + r * 8][tx];
        size_t byte = (size_t)n * (size_t)(Ks * 2) +
                      (size_t)(((unsigned)(k * 2)) ^ (unsigned)((n & 7) << 4));
        *(__half*)(ThZ + byte) = __float2half_rn(v);
    }
}

// ------------------------------------------------- f16 MFMA GEMM, TMxTN tile
// BK=64, TRIPLE-buffered LDS, 2-ahead prefetch with counted vmcnt so two
// tiles' loads stay in flight across each barrier+MFMA phase.
template <int TM, int TN, bool F16OUT>
__global__ __launch_bounds__(256, 2) void k_gemm(
    const char* __restrict__ Ah, const char* __restrict__ Bh,
    float* __restrict__ C, unsigned short* __restrict__ C16,
    int M, int N, int K, int kchunk, long partStride) {
    constexpr int MW = TM / 2, NW = TN / 2;      // wave tile
    constexpr int FM = MW / 16, FN = NW / 16;    // fragments per wave
    constexpr int CPW = (TM + TN) / 32;          // 8-row stage chunks per wave
    __shared__ __half L[3][(TM + TN) * 64];
    const int tid = threadIdx.x, w = tid >> 6, lane = tid & 63;

    const int GX = gridDim.x, GY = gridDim.y;
    const int nwg = GX * GY * gridDim.z;
    const int orig = blockIdx.x + GX * (blockIdx.y + GY * blockIdx.z);
    const int q = nwg >> 3, r = nwg & 7, xcd = orig & 7, pos = orig >> 3;
    const int wrk = (xcd < r ? xcd * (q + 1) : r * (q + 1) + (xcd - r) * q) + pos;
    const int bm = wrk % GY;
    const int t1 = wrk / GY;
    const int bn = t1 % GX, bz = t1 / GX;

    const int m0 = bm * TM, n0 = bn * TN;
    const int kbeg = bz * kchunk;
    int kend = kbeg + kchunk; if (kend > K) kend = K;
    C += (size_t)bz * (size_t)partStride;
    const size_t K2 = (size_t)K * 2;
    const int srLane = lane >> 3;         // row 0..7 within chunk
    const int scol = (lane & 7) * 16;     // byte col within 128B row-slice

    f32x4 acc[FM][FN];
#pragma unroll
    for (int i = 0; i < FM; ++i)
#pragma unroll
        for (int j = 0; j < FN; ++j) acc[i][j] = (f32x4)(0.f);

    auto STAGE = [&](int buf, int k0) {   // CPW global_load_lds per wave
#pragma unroll
        for (int i = 0; i < CPW; ++i) {
            int cid = w * CPW + i;
            bool isA = cid < TM / 8;
            int lr = (isA ? cid : cid - TM / 8) * 8;
            size_t go = (size_t)((isA ? m0 : n0) + lr + srLane) * K2 +
                        (size_t)k0 * 2 + scol;
            const char* src = isA ? Ah : Bh;
            int ldsOff = (isA ? 0 : TM * 64) + lr * 64;
            __builtin_amdgcn_global_load_lds(
                (const __attribute__((address_space(1))) void*)(src + go),
                (__attribute__((address_space(3))) void*)&L[buf][ldsOff], 16, 0, 0);
        }
    };

    const int wm = w >> 1, wn = w & 1;
    const int g = lane >> 4, rr = lane & 15;
    const int nk = (kend - kbeg + 63) / 64;

    STAGE(0, kbeg);
    if (1 < nk) STAGE(1, kbeg + 64);

    for (int t = 0; t < nk; ++t) {
        if (t + 2 < nk) {
            STAGE((t + 2) % 3, kbeg + (t + 2) * 64);
            vm_wait<2 * CPW>();           // t's loads done; t+1,t+2 in flight
        } else if (t + 1 < nk) {
            vm_wait<CPW>();
        } else {
            vm_wait<0>();
        }
        __builtin_amdgcn_s_barrier();
        const char* Lb = (const char*)L[t % 3];
#pragma unroll
        for (int kk = 0; kk < 2; ++kk) {
            f16x8 af[FM], bf[FN];
#pragma unroll
            for (int mf = 0; mf < FM; ++mf) {
                int row = wm * MW + mf * 16 + rr;
                int off = row * 128 + ((kk * 64 + g * 16) ^ ((row & 7) << 4));
                af[mf] = *(const f16x8*)(Lb + off);
            }
#pragma unroll
            for (int nf = 0; nf < FN; ++nf) {
                int row = wn * NW + nf * 16 + rr;
                int off = TM * 128 + row * 128 +
                          ((kk * 64 + g * 16) ^ ((row & 7) << 4));
                bf[nf] = *(const f16x8*)(Lb + off);
            }
#pragma unroll
            for (int mf = 0; mf < FM; ++mf)
#pragma unroll
                for (int nf = 0; nf < FN; ++nf)
                    acc[mf][nf] = __builtin_amdgcn_mfma_f32_16x16x32_f16(
                        af[mf], bf[nf], acc[mf][nf], 0, 0, 0);
        }
        __builtin_amdgcn_s_barrier();
    }

#pragma unroll
    for (int mf = 0; mf < FM; ++mf)
#pragma unroll
        for (int nf = 0; nf < FN; ++nf)
#pragma unroll
            for (int e = 0; e < 4; ++e) {
                int gm = m0 + wm * MW + mf * 16 + g * 4 + e;
                int gn = n0 + wn * NW + nf * 16 + rr;
                if (gm < M && gn < N) {
                    if (F16OUT)
                        C16[(size_t)gm * N + gn] =
                            __half_as_ushort(__float2half_rn(acc[mf][nf][e]));
                    else
                        C[(size_t)gm * N + gn] = acc[mf][nf][e];
                }
            }
}

// -------- fused patch epilogue: sum 6 partials + bias, +cls, +pos -> xtok
__global__ __launch_bounds__(256) void k_patch_asm(
    const float* __restrict__ part, const float* __restrict__ patch_b,
    const float* __restrict__ cls, const float* __restrict__ pos,
    float* __restrict__ xtok) {
    int idx = blockIdx.x * 256 + threadIdx.x;
    if (idx >= NTOK * DMODEL) return;
    int d = idx % DMODEL;
    int t = (idx / DMODEL) % LSEQ;
    int b = idx / (DMODEL * LSEQ);
    float v;
    if (t < NPATCH) {
        size_t pi = ((size_t)(b * NPATCH + t)) * DMODEL + d;
        float s = patch_b[d];
#pragma unroll
        for (int k = 0; k < 6; ++k) s += part[(size_t)k * (NPTOK * DMODEL) + pi];
        v = s;
    } else {
        v = cls[d];
    }
    xtok[idx] = v + pos[t * DMODEL + d];
}

// ------------- causal depthwise conv (K=4) + SiLU, f16 in/out, 4 d's/thread
__global__ __launch_bounds__(256) void k_conv(
    const unsigned short* __restrict__ xzH, const float* __restrict__ cw,
    const float* __restrict__ cb, char* __restrict__ uh) {
    int idx = blockIdx.x * 256 + threadIdx.x;
    if (idx >= NTOK * (DINNER / 4)) return;
    int dq = idx & (DINNER / 4 - 1);
    int t  = idx / (DINNER / 4);
    int l  = t % LSEQ;
    int d  = dq * 4;
    float4 w0 = *(const float4*)&cw[(d + 0) * 4];
    float4 w1 = *(const float4*)&cw[(d + 1) * 4];
    float4 w2 = *(const float4*)&cw[(d + 2) * 4];
    float4 w3 = *(const float4*)&cw[(d + 3) * 4];
    float4 acc = *(const float4*)&cb[d];
#pragma unroll
    for (int j = 0; j < 4; ++j) {
        int ls = l - 3 + j;
        if (ls >= 0) {
            union { ushort4 v; __half h[4]; } xu;
            xu.v = *(const ushort4*)&xzH[(size_t)(t - 3 + j) * (2 * DINNER) + d];
            acc.x += (&w0.x)[j] * __half2float(xu.h[0]);
            acc.y += (&w1.x)[j] * __half2float(xu.h[1]);
            acc.z += (&w2.x)[j] * __half2float(xu.h[2]);
            acc.w += (&w3.x)[j] * __half2float(xu.h[3]);
        }
    }
    float4 uv = make_float4(sp_silu(acc.x), sp_silu(acc.y),
                            sp_silu(acc.z), sp_silu(acc.w));
    store_f16x4(uh, t, d, DINNER, uv);
}

// ------- selective scan v6b: fused dt-proj + LDS stage (f16 u) + pipelined
// batch-8 recurrence + z register-prefetch + fused gate (f16 out).
// grid (DINNER/16, BATCH), 256 thr.
__global__ __launch_bounds__(256) void k_scan2(
    const char* __restrict__ uH, const float* __restrict__ dbc,
    const float* __restrict__ dtw, const float* __restrict__ dtb,
    const float* __restrict__ Alog, const float* __restrict__ Dp,
    const unsigned short* __restrict__ xzH, char* __restrict__ gh) {
    __shared__ float uS[LPAD * 16];
    __shared__ float dS[LPAD * 16];   // dt in, y out (slot l dead after iter l)
    __shared__ float bS[LPAD * 16];
    __shared__ float cS[LPAD * 16];
    __shared__ float wS[DRANK * 16];  // dt_w columns d0..d0+15
    const int tid = threadIdx.x;
    const int b = blockIdx.y, d0 = blockIdx.x * 16;

    // phase 0: dtw columns to LDS
    for (int i = tid; i < DRANK * 16; i += 256)
        wS[i] = dtw[(size_t)(i >> 4) * DINNER + d0 + (i & 15)];
    __syncthreads();

    // phase 1a: stage u (f16 swizzled -> fp32 LDS); zero-fill pad rows
    for (int i = tid; i < LPAD * 2; i += 256) {
        int l = i >> 1, jj = i & 1;
        float* dst = &uS[l * 16 + jj * 8];
        if (l >= LSEQ) {
#pragma unroll
            for (int e = 0; e < 8; ++e) dst[e] = 0.f;
            continue;
        }
        int t = b * LSEQ + l;
        size_t byte = (size_t)t * (DINNER * 2) +
                      (size_t)(((unsigned)(d0 * 2 + jj * 16)) ^ (unsigned)((t & 7) << 4));
        union { us8 v; __half h[8]; } uu;
        uu.v = *(const us8*)(uH + byte);
#pragma unroll
        for (int e = 0; e < 8; ++e) dst[e] = __half2float(uu.h[e]);
    }

    // phase 1b: stage B/C, compute dt = softplus(r@dtw + b); zero-fill pad rows
    const float* dbcB = dbc + ((size_t)b * LSEQ) * 64;
    for (int i = tid; i < LPAD * 4; i += 256) {
        int l = i >> 2, j = (i & 3) << 2;
        if (l >= LSEQ) {
            float4 z = make_float4(0.f, 0.f, 0.f, 0.f);
            *(float4*)&dS[l * 16 + j] = z;
            *(float4*)&bS[l * 16 + j] = z;
            *(float4*)&cS[l * 16 + j] = z;
            continue;
        }
        *(float4*)&bS[l * 16 + j] = *(const float4*)&dbcB[(size_t)l * 64 + DRANK + j];
        *(float4*)&cS[l * 16 + j] = *(const float4*)&dbcB[(size_t)l * 64 + DRANK + 16 + j];
        float4 acc = *(const float4*)&dtb[d0 + j];
#pragma unroll
        for (int kq = 0; kq < DRANK / 4; ++kq) {
            float4 r4 = *(const float4*)&dbcB[(size_t)l * 64 + kq * 4];
#pragma unroll
            for (int m = 0; m < 4; ++m) {
                float rv = (&r4.x)[m];
                float4 w4 = *(const float4*)&wS[(kq * 4 + m) * 16 + j];
                acc.x += rv * w4.x; acc.y += rv * w4.y;
                acc.z += rv * w4.z; acc.w += rv * w4.w;
            }
        }
        dS[l * 16 + j + 0] = sp_softplus(acc.x);
        dS[l * 16 + j + 1] = sp_softplus(acc.y);
        dS[l * 16 + j + 2] = sp_softplus(acc.z);
        dS[l * 16 + j + 3] = sp_softplus(acc.w);
    }
    const int n = tid & 15, dsub = tid >> 4;
    const int d = d0 + dsub;
    const float A  = -__expf(Alog[d * NSTATE + n]);
    const float Dv = Dp[d];

    // z register-prefetch (independent of scan; HBM latency hides under phase 2)
    ushort4 zreg[4];
#pragma unroll
    for (int it = 0; it < 4; ++it) {
        int i = tid + it * 256;
        if (i < LSEQ * 4) {
            int l = i >> 2, j = (i & 3) << 2;
            int t = b * LSEQ + l;
            zreg[it] = *(const ushort4*)&xzH[(size_t)t * (2 * DINNER) + DINNER + d0 + j];
        }
    }
    __syncthreads();

    // phase 2: batch-8 software-pipelined recurrence.
    // dsub columns are wave-private, so in-loop dS y-writes never race.
    float hn = 0.f;
    float dtc[8], uvc[8], Bnc[8], Cnc[8];
#pragma unroll
    for (int i = 0; i < 8; ++i) {
        int o = i * 16;
        dtc[i] = dS[o + dsub]; uvc[i] = uS[o + dsub];
        Bnc[i] = bS[o + n];    Cnc[i] = cS[o + n];
    }
    for (int lb = 0; lb < LPAD; lb += 8) {
        float dtN[8], uvN[8], BnN[8], CnN[8];
        if (lb + 8 < LPAD) {
#pragma unroll
            for (int i = 0; i < 8; ++i) {
                int o = (lb + 8 + i) * 16;
                dtN[i] = dS[o + dsub]; uvN[i] = uS[o + dsub];
                BnN[i] = bS[o + n];    CnN[i] = cS[o + n];
            }
        } else {
#pragma unroll
            for (int i = 0; i < 8; ++i) { dtN[i] = uvN[i] = BnN[i] = CnN[i] = 0.f; }
        }
        float a8[8], b8[8], p8[8];
#pragma unroll
        for (int i = 0; i < 8; ++i) {
            a8[i] = __expf(dtc[i] * A);
            b8[i] = dtc[i] * uvc[i] * Bnc[i];
        }
#pragma unroll
        for (int i = 0; i < 8; ++i) {
            hn = a8[i] * hn + b8[i];
            p8[i] = hn * Cnc[i];
        }
        row_sum16v<8>(p8);
#pragma unroll
        for (int i = 0; i < 8; ++i)
            if (n == 15) dS[(lb + i) * 16 + dsub] = p8[i] + uvc[i] * Dv;
#pragma unroll
        for (int i = 0; i < 8; ++i) {
            dtc[i] = dtN[i]; uvc[i] = uvN[i]; Bnc[i] = BnN[i]; Cnc[i] = CnN[i];
        }
    }
    __syncthreads();

    // phase 3: fused gate g = y * silu(z); z from registers, vectorized stores
#pragma unroll
    for (int it = 0; it < 4; ++it) {
        int i = tid + it * 256;
        if (i < LSEQ * 4) {
            int l = i >> 2, j = (i & 3) << 2;
            int t = b * LSEQ + l;
            union { ushort4 v; __half h[4]; } zu;
            zu.v = zreg[it];
            float4 g4 = make_float4(
                dS[l * 16 + j + 0] * sp_silu(__half2float(zu.h[0])),
                dS[l * 16 + j + 1] * sp_silu(__half2float(zu.h[1])),
                dS[l * 16 + j + 2] * sp_silu(__half2float(zu.h[2])),
                dS[l * 16 + j + 3] * sp_silu(__half2float(zu.h[3])));
            store_f16x4(gh, t, d0 + j, DINNER, g4);
        }
    }
}

// ------------- head stage 1: final residual reduce (8 rows only) + LN -> xr
__global__ __launch_bounds__(256) void k_head_ln(
    const float* __restrict__ part, const float* __restrict__ xtok,
    const float* __restrict__ lnw, const float* __restrict__ lnb,
    float* __restrict__ xr) {
    __shared__ float red[8];
    int b = blockIdx.x, tid = threadIdx.x;
    size_t base = ((size_t)(b * LSEQ + NPATCH)) * DMODEL;
    float v0 = xtok[base + tid], v1 = xtok[base + tid + 256];
#pragma unroll
    for (int k = 0; k < 2; ++k) {
        v0 += part[(size_t)k * (NTOK * DMODEL) + base + tid];
        v1 += part[(size_t)k * (NTOK * DMODEL) + base + tid + 256];
    }
    float2 t2 = block_reduce2(v0 + v1, v0 * v0 + v1 * v1, red);
    float mean = t2.x * (1.0f / DMODEL);
    float var  = t2.y * (1.0f / DMODEL) - mean * mean;
    float rstd = 1.0f / sqrtf(var + 1e-5f);
    xr[b * DMODEL + tid]       = (v0 - mean) * rstd * lnw[tid] + lnb[tid];
    xr[b * DMODEL + tid + 256] = (v1 - mean) * rstd * lnw[tid + 256] + lnb[tid + 256];
}

// ------------- head stage 2: k-split FC partials. grid (4, BATCH, 8)
__global__ __launch_bounds__(256) void k_head_fc(
    const float* __restrict__ xr, const float* __restrict__ hw,
    float* __restrict__ hpart) {
    __shared__ float xs[64];
    int tid = threadIdx.x;
    int c = blockIdx.x * 256 + tid;
    int b = blockIdx.y, ks = blockIdx.z;
    if (tid < 64) xs[tid] = xr[b * DMODEL + ks * 64 + tid];
    __syncthreads();
    if (c >= NCLS) return;
    float acc = 0.f;
#pragma unroll 8
    for (int k = 0; k < 64; ++k) acc += xs[k] * hw[(size_t)(ks * 64 + k) * NCLS + c];
    hpart[(size_t)(ks * BATCH + b) * NCLS + c] = acc;
}

// ------------- head stage 3: sum 8 partials + bias -> out
__global__ __launch_bounds__(256) void k_head_red(
    const float* __restrict__ hpart, const float* __restrict__ hb,
    float* __restrict__ out) {
    int i = blockIdx.x * 256 + threadIdx.x;
    if (i >= BATCH * NCLS) return;
    int b = i / NCLS, c = i % NCLS;
    float s = hb[c];
#pragma unroll
    for (int ks = 0; ks < 8; ++ks) s += hpart[(size_t)(ks * BATCH + b) * NCLS + c];
    out[i] = s;
}

extern "C" void kernel_launch(void* const* d_in, const int* in_sizes, int n_in,
                              void* d_out, int out_size, void* d_ws, size_t ws_size,
                              hipStream_t stream) {
    const float* img     = (const float*)d_in[0];
    const float* plnw    = (const float*)d_in[1];
    const float* plnb    = (const float*)d_in[2];
    const float* patch_w = (const float*)d_in[3];
    const float* patch_b = (const float*)d_in[4];
    const float* pos     = (const float*)d_in[5];
    const float* cls     = (const float*)d_in[6];
    const float* ln_w    = (const float*)d_in[7];
    const float* ln_b    = (const float*)d_in[8];
    const float* in_w    = (const float*)d_in[9];
    const float* conv_w  = (const float*)d_in[10];
    const float* conv_b  = (const float*)d_in[11];
    const float* xproj   = (const float*)d_in[12];
    const float* dt_w    = (const float*)d_in[13];
    const float* dt_b    = (const float*)d_in[14];
    const float* A_log   = (const float*)d_in[15];
    const float* Dp      = (const float*)d_in[16];
    const float* out_w   = (const float*)d_in[17];
    const float* hlnw    = (const float*)d_in[18];
    const float* hlnb    = (const float*)d_in[19];
    const float* head_w  = (const float*)d_in[20];
    const float* head_b  = (const float*)d_in[21];
    float* out = (float*)d_out;

    char* p = (char*)d_ws;
    auto alloc = [&](size_t bytes) { char* r = p; p += (bytes + 255) & ~(size_t)255; return r; };
    float* xtok = (float*)alloc((size_t)NTOK * DMODEL * 4);
    unsigned short* xzH = (unsigned short*)alloc((size_t)NTOK * 2 * DINNER * 2);
    float* dbc  = (float*)alloc((size_t)NTOK * 64 * 4);
    float* part = (float*)alloc((size_t)6 * NPTOK * DMODEL * 4);
    float* xr   = (float*)alloc((size_t)BATCH * DMODEL * 4);
    float* hpart= (float*)alloc((size_t)8 * BATCH * NCLS * 4);
    char* ylnH = alloc((size_t)MPAD * DMODEL * 2);
    char* uH   = alloc((size_t)MPAD * DINNER * 2);
    char* gH   = alloc((size_t)MPAD * DINNER * 2);
    char* XpH  = alloc((size_t)MPAD * PDIM * 2);
    char* inTH  = alloc((size_t)NLAYER * 2 * DINNER * DMODEL * 2);
    char* outTH = alloc((size_t)NLAYER * DMODEL * DINNER * 2);
    char* patTH = alloc((size_t)DMODEL * PDIM * 2);
    char* xprTH = alloc((size_t)NLAYER * 128 * DINNER * 2);

    const size_t IN_T_B  = (size_t)2 * DINNER * DMODEL * 2;   // bytes/layer
    const size_t OUT_T_B = (size_t)DMODEL * DINNER * 2;
    const size_t XPR_T_B = (size_t)128 * DINNER * 2;

    // ---- one-time weight transpose + f16 cast (per call) ----
    k_wT<<<dim3(2 * DINNER / 32, DMODEL / 32, NLAYER), dim3(32, 8), 0, stream>>>(
        in_w, inTH, DMODEL, 2 * DINNER, (size_t)DMODEL * 2 * DINNER, IN_T_B);
    k_wT<<<dim3(DMODEL / 32, DINNER / 32, NLAYER), dim3(32, 8), 0, stream>>>(
        out_w, outTH, DINNER, DMODEL, (size_t)DINNER * DMODEL, OUT_T_B);
    k_wT<<<dim3(DMODEL / 32, PDIM / 32, 1), dim3(32, 8), 0, stream>>>(
        patch_w, patTH, PDIM, DMODEL, 0, 0);
    k_wT<<<dim3(128 / 32, DINNER / 32, NLAYER), dim3(32, 8), 0, stream>>>(
        xproj, xprTH, DINNER, 64, (size_t)DINNER * 64, XPR_T_B);

    // ---- patch embedding (split-K 6, kchunk 640 = 10 K-steps) ----
    k_patch_ln<<<NPTOK, 256, 0, stream>>>(img, plnw, plnb, XpH);
    k_gemm<64, 128, false><<<dim3(4, 25, 6), 256, 0, stream>>>(
        XpH, patTH, part, nullptr, NPTOK, DMODEL, PDIM, 640, (long)NPTOK * DMODEL);
    k_patch_asm<<<(NTOK * DMODEL + 255) / 256, 256, 0, stream>>>(
        part, patch_b, cls, pos, xtok);

    // ---- mamba layers ----
    for (int i = 0; i < NLAYER; ++i) {
        if (i == 0) {
            k_ln<<<(NTOK + 3) / 4, 256, 0, stream>>>(xtok, ln_w, ln_b, ylnH);
        } else {
            k_red_ln<<<(NTOK + 3) / 4, 256, 0, stream>>>(
                part, xtok, ln_w + i * DMODEL, ln_b + i * DMODEL, ylnH);
        }
        k_gemm<64, 128, true><<<dim3(16, 25, 1), 256, 0, stream>>>(
            ylnH, inTH + i * IN_T_B, nullptr, xzH, NTOK, 2 * DINNER, DMODEL, DMODEL, 0);
        k_conv<<<(NTOK * (DINNER / 4) + 255) / 256, 256, 0, stream>>>(
            xzH, conv_w + (size_t)i * DINNER * 4, conv_b + (size_t)i * DINNER, uH);
        // xproj single-pass (no split-K): writes dbc directly
        k_gemm<64, 64, false><<<dim3(1, 25, 1), 256, 0, stream>>>(
            uH, xprTH + i * XPR_T_B, dbc, nullptr, NTOK, 64, DINNER, DINNER, 0);
        k_scan2<<<dim3(DINNER / 16, BATCH), 256, 0, stream>>>(
            uH, dbc, dt_w + (size_t)i * DRANK * DINNER, dt_b + (size_t)i * DINNER,
            A_log + (size_t)i * DINNER * NSTATE, Dp + (size_t)i * DINNER,
            xzH, gH);
        k_gemm<64, 128, false><<<dim3(4, 25, 2), 256, 0, stream>>>(
            gH, outTH + i * OUT_T_B, part, nullptr, NTOK, DMODEL, DINNER, 512,
            (long)NTOK * DMODEL);
    }

    // ---- head: residual reduce (8 rows) + LN, k-split FC, reduce ----
    k_head_ln<<<BATCH, 256, 0, stream>>>(part, xtok, hlnw, hlnb, xr);
    k_head_fc<<<dim3(4, BATCH, 8), 256, 0, stream>>>(xr, head_w, hpart);
    k_head_red<<<(BATCH * NCLS + 255) / 256, 256, 0, stream>>>(hpart, head_b, out);
}

// Round 19
// 545.372 us; speedup vs baseline: 1.0314x; 1.0314x over previous
//
#include <hip/hip_runtime.h>
#include <hip/hip_fp16.h>
#include <math.h>

#define BATCH   8
#define LSEQ    197
#define LPAD    200                // LSEQ padded to multiple of 8 for scan batches
#define NPATCH  196
#define NPTOK   (BATCH * NPATCH)   // 1568
#define NTOK    (BATCH * LSEQ)     // 1576
#define MPAD    1664               // padded row count for f16 act arrays (>= 25*64)
#define DMODEL  512
#define DINNER  1024
#define NSTATE  16
#define DRANK   32
#define NLAYER  8
#define NCLS    1000
#define PDIM    3840               // 16*16*15

typedef _Float16 f16x8 __attribute__((ext_vector_type(8)));
typedef float    f32x4 __attribute__((ext_vector_type(4)));
typedef unsigned short us8 __attribute__((ext_vector_type(8)));

// Fast transcendentals (v_exp/v_log/v_rcp based; ~1e-7 rel err vs 0.0156 absmax)
__device__ __forceinline__ float f_rcp(float x) { return __builtin_amdgcn_rcpf(x); }
__device__ __forceinline__ float sp_silu(float x) { return x * f_rcp(1.0f + __expf(-x)); }
__device__ __forceinline__ float sp_softplus(float x) {
    return x > 20.0f ? x : __logf(1.0f + __expf(x));
}

template <int N>
__device__ __forceinline__ void vm_wait() {
    if constexpr (N == 0)       asm volatile("s_waitcnt vmcnt(0)" ::: "memory");
    else if constexpr (N == 4)  asm volatile("s_waitcnt vmcnt(4)" ::: "memory");
    else if constexpr (N == 6)  asm volatile("s_waitcnt vmcnt(6)" ::: "memory");
    else if constexpr (N == 8)  asm volatile("s_waitcnt vmcnt(8)" ::: "memory");
    else if constexpr (N == 12) asm volatile("s_waitcnt vmcnt(12)" ::: "memory");
}

// N interleaved 16-lane row sums (row_shr DPP tree); lane 15 of each row gets
// the sum. dpp_ctrl must be a literal constant -> explicit 4-step expansion.
#define DPP_ROW_SHR_STEP(P, NB, CTRL)                                          \
    {                                                                          \
        float t_[NB];                                                          \
        _Pragma("unroll")                                                      \
        for (int i_ = 0; i_ < NB; ++i_)                                        \
            t_[i_] = __int_as_float(__builtin_amdgcn_update_dpp(               \
                0, __float_as_int(P[i_]), CTRL, 0xF, 0xF, true));              \
        _Pragma("unroll")                                                      \
        for (int i_ = 0; i_ < NB; ++i_) P[i_] += t_[i_];                       \
    }

template <int NB>
__device__ __forceinline__ void row_sum16v(float* p) {
    DPP_ROW_SHR_STEP(p, NB, 0x111);   // row_shr:1
    DPP_ROW_SHR_STEP(p, NB, 0x112);   // row_shr:2
    DPP_ROW_SHR_STEP(p, NB, 0x114);   // row_shr:4
    DPP_ROW_SHR_STEP(p, NB, 0x118);   // row_shr:8
}

// Store f16 value at swizzled position (row, k) of a [*][K] f16 array.
// Swizzle: byte-in-row ^= (row&7)<<4  (permutes 16B blocks within 128B chunks).
__device__ __forceinline__ void store_f16(char* __restrict__ Hb,
                                          int row, int k, int K, float v) {
    size_t byte = (size_t)row * (size_t)(K * 2) +
                  (size_t)(((unsigned)(k * 2)) ^ (unsigned)((row & 7) << 4));
    *(__half*)(Hb + byte) = __float2half_rn(v);
}

// 4 consecutive k (k4 multiple of 4): one 8B store (stays inside a 16B block).
__device__ __forceinline__ void store_f16x4(char* __restrict__ Hb,
                                            int row, int k4, int K, float4 v) {
    size_t byte = (size_t)row * (size_t)(K * 2) +
                  (size_t)(((unsigned)(k4 * 2)) ^ (unsigned)((row & 7) << 4));
    *(ushort4*)(Hb + byte) = make_ushort4(
        __half_as_ushort(__float2half_rn(v.x)), __half_as_ushort(__float2half_rn(v.y)),
        __half_as_ushort(__float2half_rn(v.z)), __half_as_ushort(__float2half_rn(v.w)));
}

// 256-thread block reduction of two values; lds must be 8 floats.
__device__ __forceinline__ float2 block_reduce2(float a, float b, float* lds) {
#pragma unroll
    for (int off = 32; off > 0; off >>= 1) {
        a += __shfl_down(a, off);
        b += __shfl_down(b, off);
    }
    int lane = threadIdx.x & 63, w = threadIdx.x >> 6;
    if (lane == 0) { lds[w] = a; lds[4 + w] = b; }
    __syncthreads();
    float sa = lds[0] + lds[1] + lds[2] + lds[3];
    float sb = lds[4] + lds[5] + lds[6] + lds[7];
    return make_float2(sa, sb);
}

// ---------------------------------------------------------------- patch stage
__global__ __launch_bounds__(256) void k_patch_ln(
    const float* __restrict__ img, const float* __restrict__ lnw,
    const float* __restrict__ lnb, char* __restrict__ Xph) {
    __shared__ float vals[PDIM];
    __shared__ float red[8];
    int tok = blockIdx.x;
    int b = tok / NPATCH, p = tok % NPATCH;
    int gy = p / 14, gx = p % 14;
    int tid = threadIdx.x;
    int py = tid >> 4, px = tid & 15;
    int h0 = gy * 16 + py, w0 = gx * 16 + px;
    const int dh[5] = {0, 0, 0, -1, 1};
    const int dw[5] = {0, -1, 1, 0, 0};
    float s = 0.f, ss = 0.f;
#pragma unroll
    for (int c = 0; c < 15; ++c) {
        int g = c / 3, ch = c % 3;
        int h = h0 + dh[g], w = w0 + dw[g];
        float v = 0.f;
        if ((unsigned)h < 224u && (unsigned)w < 224u)
            v = img[((b * 3 + ch) * 224 + h) * 224 + w];
        vals[tid * 15 + c] = v;
        s += v; ss += v * v;
    }
    float2 t2 = block_reduce2(s, ss, red);
    float mean = t2.x * (1.0f / PDIM);
    float var  = t2.y * (1.0f / PDIM) - mean * mean;
    float rstd = 1.0f / sqrtf(var + 1e-5f);
    for (int j = 0; j < 15; ++j) {
        int e = tid + j * 256;
        float v = (vals[e] - mean) * rstd * lnw[e] + lnb[e];
        store_f16(Xph, tok, e, PDIM, v);
    }
}

// ------------------------------------------------------------------- token LN
__global__ __launch_bounds__(256) void k_ln(
    const float* __restrict__ x, const float* __restrict__ w,
    const float* __restrict__ b, char* __restrict__ yh) {
    __shared__ float red[8];
    int t = blockIdx.x, tid = threadIdx.x;
    const float* xr = x + (size_t)t * DMODEL;
    float v0 = xr[tid], v1 = xr[tid + 256];
    float2 t2 = block_reduce2(v0 + v1, v0 * v0 + v1 * v1, red);
    float mean = t2.x * (1.0f / DMODEL);
    float var  = t2.y * (1.0f / DMODEL) - mean * mean;
    float rstd = 1.0f / sqrtf(var + 1e-5f);
    store_f16(yh, t, tid,       DMODEL, (v0 - mean) * rstd * w[tid]       + b[tid]);
    store_f16(yh, t, tid + 256, DMODEL, (v1 - mean) * rstd * w[tid + 256] + b[tid + 256]);
}

// ------------- fused: xtok += sum(part[0..1]); yln = LN(xtok) (f16 out)
__global__ __launch_bounds__(256) void k_red_ln(
    const float* __restrict__ part, float* __restrict__ xtok,
    const float* __restrict__ w, const float* __restrict__ b,
    char* __restrict__ yh) {
    __shared__ float red[8];
    int t = blockIdx.x, tid = threadIdx.x;
    size_t base = (size_t)t * DMODEL;
    float v0 = xtok[base + tid], v1 = xtok[base + tid + 256];
#pragma unroll
    for (int k = 0; k < 2; ++k) {
        v0 += part[(size_t)k * (NTOK * DMODEL) + base + tid];
        v1 += part[(size_t)k * (NTOK * DMODEL) + base + tid + 256];
    }
    xtok[base + tid] = v0;
    xtok[base + tid + 256] = v1;
    float2 t2 = block_reduce2(v0 + v1, v0 * v0 + v1 * v1, red);
    float mean = t2.x * (1.0f / DMODEL);
    float var  = t2.y * (1.0f / DMODEL) - mean * mean;
    float rstd = 1.0f / sqrtf(var + 1e-5f);
    store_f16(yh, t, tid,       DMODEL, (v0 - mean) * rstd * w[tid]       + b[tid]);
    store_f16(yh, t, tid + 256, DMODEL, (v1 - mean) * rstd * w[tid + 256] + b[tid + 256]);
}

// --------------------------------------------- weight transpose + f16 cast
__global__ __launch_bounds__(256) void k_wT(
    const float* __restrict__ W, char* __restrict__ Th,
    int Ks, int Ns, size_t wStride, size_t tByteStride) {
    __shared__ float t[32][33];
    int z = blockIdx.z;
    const float* Wz = W + (size_t)z * wStride;
    char* ThZ = Th + (size_t)z * tByteStride;
    int n0 = blockIdx.x * 32, k0 = blockIdx.y * 32;
    int tx = threadIdx.x, ty = threadIdx.y;
#pragma unroll
    for (int r = 0; r < 4; ++r) {
        int k = k0 + ty + r * 8, n = n0 + tx;
        t[tx][ty + r * 8] = (n < Ns) ? Wz[(size_t)k * Ns + n] : 0.f;
    }
    __syncthreads();
#pragma unroll
    for (int r = 0; r < 4; ++r) {
        int n = n0 + ty + r * 8, k = k0 + tx;
        float v = t[ty + r * 8][tx];
        size_t byte = (size_t)n * (size_t)(Ks * 2) +
                      (size_t)(((unsigned)(k * 2)) ^ (unsigned)((n & 7) << 4));
        *(__half*)(ThZ + byte) = __float2half_rn(v);
    }
}

// ------------------------------------------------- f16 MFMA GEMM, TMxTN tile
// BK=64, TRIPLE-buffered LDS, 2-ahead prefetch with counted vmcnt so two
// tiles' loads stay in flight across each barrier+MFMA phase.
template <int TM, int TN, bool F16OUT>
__global__ __launch_bounds__(256, 2) void k_gemm(
    const char* __restrict__ Ah, const char* __restrict__ Bh,
    float* __restrict__ C, unsigned short* __restrict__ C16,
    int M, int N, int K, int kchunk, long partStride) {
    constexpr int MW = TM / 2, NW = TN / 2;      // wave tile
    constexpr int FM = MW / 16, FN = NW / 16;    // fragments per wave
    constexpr int CPW = (TM + TN) / 32;          // 8-row stage chunks per wave
    __shared__ __half L[3][(TM + TN) * 64];
    const int tid = threadIdx.x, w = tid >> 6, lane = tid & 63;

    const int GX = gridDim.x, GY = gridDim.y;
    const int nwg = GX * GY * gridDim.z;
    const int orig = blockIdx.x + GX * (blockIdx.y + GY * blockIdx.z);
    const int q = nwg >> 3, r = nwg & 7, xcd = orig & 7, pos = orig >> 3;
    const int wrk = (xcd < r ? xcd * (q + 1) : r * (q + 1) + (xcd - r) * q) + pos;
    const int bm = wrk % GY;
    const int t1 = wrk / GY;
    const int bn = t1 % GX, bz = t1 / GX;

    const int m0 = bm * TM, n0 = bn * TN;
    const int kbeg = bz * kchunk;
    int kend = kbeg + kchunk; if (kend > K) kend = K;
    C += (size_t)bz * (size_t)partStride;
    const size_t K2 = (size_t)K * 2;
    const int srLane = lane >> 3;         // row 0..7 within chunk
    const int scol = (lane & 7) * 16;     // byte col within 128B row-slice

    f32x4 acc[FM][FN];
#pragma unroll
    for (int i = 0; i < FM; ++i)
#pragma unroll
        for (int j = 0; j < FN; ++j) acc[i][j] = (f32x4)(0.f);

    auto STAGE = [&](int buf, int k0) {   // CPW global_load_lds per wave
#pragma unroll
        for (int i = 0; i < CPW; ++i) {
            int cid = w * CPW + i;
            bool isA = cid < TM / 8;
            int lr = (isA ? cid : cid - TM / 8) * 8;
            size_t go = (size_t)((isA ? m0 : n0) + lr + srLane) * K2 +
                        (size_t)k0 * 2 + scol;
            const char* src = isA ? Ah : Bh;
            int ldsOff = (isA ? 0 : TM * 64) + lr * 64;
            __builtin_amdgcn_global_load_lds(
                (const __attribute__((address_space(1))) void*)(src + go),
                (__attribute__((address_space(3))) void*)&L[buf][ldsOff], 16, 0, 0);
        }
    };

    const int wm = w >> 1, wn = w & 1;
    const int g = lane >> 4, rr = lane & 15;
    const int nk = (kend - kbeg + 63) / 64;

    STAGE(0, kbeg);
    if (1 < nk) STAGE(1, kbeg + 64);

    for (int t = 0; t < nk; ++t) {
        if (t + 2 < nk) {
            STAGE((t + 2) % 3, kbeg + (t + 2) * 64);
            vm_wait<2 * CPW>();           // t's loads done; t+1,t+2 in flight
        } else if (t + 1 < nk) {
            vm_wait<CPW>();
        } else {
            vm_wait<0>();
        }
        __builtin_amdgcn_s_barrier();
        const char* Lb = (const char*)L[t % 3];
#pragma unroll
        for (int kk = 0; kk < 2; ++kk) {
            f16x8 af[FM], bf[FN];
#pragma unroll
            for (int mf = 0; mf < FM; ++mf) {
                int row = wm * MW + mf * 16 + rr;
                int off = row * 128 + ((kk * 64 + g * 16) ^ ((row & 7) << 4));
                af[mf] = *(const f16x8*)(Lb + off);
            }
#pragma unroll
            for (int nf = 0; nf < FN; ++nf) {
                int row = wn * NW + nf * 16 + rr;
                int off = TM * 128 + row * 128 +
                          ((kk * 64 + g * 16) ^ ((row & 7) << 4));
                bf[nf] = *(const f16x8*)(Lb + off);
            }
#pragma unroll
            for (int mf = 0; mf < FM; ++mf)
#pragma unroll
                for (int nf = 0; nf < FN; ++nf)
                    acc[mf][nf] = __builtin_amdgcn_mfma_f32_16x16x32_f16(
                        af[mf], bf[nf], acc[mf][nf], 0, 0, 0);
        }
        __builtin_amdgcn_s_barrier();
    }

#pragma unroll
    for (int mf = 0; mf < FM; ++mf)
#pragma unroll
        for (int nf = 0; nf < FN; ++nf)
#pragma unroll
            for (int e = 0; e < 4; ++e) {
                int gm = m0 + wm * MW + mf * 16 + g * 4 + e;
                int gn = n0 + wn * NW + nf * 16 + rr;
                if (gm < M && gn < N) {
                    if (F16OUT)
                        C16[(size_t)gm * N + gn] =
                            __half_as_ushort(__float2half_rn(acc[mf][nf][e]));
                    else
                        C[(size_t)gm * N + gn] = acc[mf][nf][e];
                }
            }
}

// ------------------------------------------------------ split-K reduce
template <int SK, bool ACC>
__global__ __launch_bounds__(256) void k_reduce(
    const float* __restrict__ part, float* __restrict__ out, int total, int stride) {
    int i = blockIdx.x * 256 + threadIdx.x;
    if (i >= total) return;
    float s = 0.f;
#pragma unroll
    for (int k = 0; k < SK; ++k) s += part[(size_t)k * stride + i];
    out[i] = ACC ? out[i] + s : s;
}

// -------- fused patch epilogue: sum 4 partials + bias, +cls, +pos -> xtok
__global__ __launch_bounds__(256) void k_patch_asm(
    const float* __restrict__ part, const float* __restrict__ patch_b,
    const float* __restrict__ cls, const float* __restrict__ pos,
    float* __restrict__ xtok) {
    int idx = blockIdx.x * 256 + threadIdx.x;
    if (idx >= NTOK * DMODEL) return;
    int d = idx % DMODEL;
    int t = (idx / DMODEL) % LSEQ;
    int b = idx / (DMODEL * LSEQ);
    float v;
    if (t < NPATCH) {
        size_t pi = ((size_t)(b * NPATCH + t)) * DMODEL + d;
        float s = patch_b[d];
#pragma unroll
        for (int k = 0; k < 4; ++k) s += part[(size_t)k * (NPTOK * DMODEL) + pi];
        v = s;
    } else {
        v = cls[d];
    }
    xtok[idx] = v + pos[t * DMODEL + d];
}

// ------------- causal depthwise conv (K=4) + SiLU, f16 in/out, 4 d's/thread
__global__ __launch_bounds__(256) void k_conv(
    const unsigned short* __restrict__ xzH, const float* __restrict__ cw,
    const float* __restrict__ cb, char* __restrict__ uh) {
    int idx = blockIdx.x * 256 + threadIdx.x;
    if (idx >= NTOK * (DINNER / 4)) return;
    int dq = idx & (DINNER / 4 - 1);
    int t  = idx / (DINNER / 4);
    int l  = t % LSEQ;
    int d  = dq * 4;
    float4 w0 = *(const float4*)&cw[(d + 0) * 4];
    float4 w1 = *(const float4*)&cw[(d + 1) * 4];
    float4 w2 = *(const float4*)&cw[(d + 2) * 4];
    float4 w3 = *(const float4*)&cw[(d + 3) * 4];
    float4 acc = *(const float4*)&cb[d];
#pragma unroll
    for (int j = 0; j < 4; ++j) {
        int ls = l - 3 + j;
        if (ls >= 0) {
            union { ushort4 v; __half h[4]; } xu;
            xu.v = *(const ushort4*)&xzH[(size_t)(t - 3 + j) * (2 * DINNER) + d];
            acc.x += (&w0.x)[j] * __half2float(xu.h[0]);
            acc.y += (&w1.x)[j] * __half2float(xu.h[1]);
            acc.z += (&w2.x)[j] * __half2float(xu.h[2]);
            acc.w += (&w3.x)[j] * __half2float(xu.h[3]);
        }
    }
    float4 uv = make_float4(sp_silu(acc.x), sp_silu(acc.y),
                            sp_silu(acc.z), sp_silu(acc.w));
    store_f16x4(uh, t, d, DINNER, uv);
}

// ------- selective scan v6b: fused dt-proj + LDS stage (f16 u) + pipelined
// batch-8 recurrence + z register-prefetch + fused gate (f16 out).
// grid (DINNER/16, BATCH), 256 thr.
__global__ __launch_bounds__(256) void k_scan2(
    const char* __restrict__ uH, const float* __restrict__ dbc,
    const float* __restrict__ dtw, const float* __restrict__ dtb,
    const float* __restrict__ Alog, const float* __restrict__ Dp,
    const unsigned short* __restrict__ xzH, char* __restrict__ gh) {
    __shared__ float uS[LPAD * 16];
    __shared__ float dS[LPAD * 16];   // dt in, y out (slot l dead after iter l)
    __shared__ float bS[LPAD * 16];
    __shared__ float cS[LPAD * 16];
    __shared__ float wS[DRANK * 16];  // dt_w columns d0..d0+15
    const int tid = threadIdx.x;
    const int b = blockIdx.y, d0 = blockIdx.x * 16;

    // phase 0: dtw columns to LDS
    for (int i = tid; i < DRANK * 16; i += 256)
        wS[i] = dtw[(size_t)(i >> 4) * DINNER + d0 + (i & 15)];
    __syncthreads();

    // phase 1a: stage u (f16 swizzled -> fp32 LDS); zero-fill pad rows
    for (int i = tid; i < LPAD * 2; i += 256) {
        int l = i >> 1, jj = i & 1;
        float* dst = &uS[l * 16 + jj * 8];
        if (l >= LSEQ) {
#pragma unroll
            for (int e = 0; e < 8; ++e) dst[e] = 0.f;
            continue;
        }
        int t = b * LSEQ + l;
        size_t byte = (size_t)t * (DINNER * 2) +
                      (size_t)(((unsigned)(d0 * 2 + jj * 16)) ^ (unsigned)((t & 7) << 4));
        union { us8 v; __half h[8]; } uu;
        uu.v = *(const us8*)(uH + byte);
#pragma unroll
        for (int e = 0; e < 8; ++e) dst[e] = __half2float(uu.h[e]);
    }

    // phase 1b: stage B/C, compute dt = softplus(r@dtw + b); zero-fill pad rows
    const float* dbcB = dbc + ((size_t)b * LSEQ) * 64;
    for (int i = tid; i < LPAD * 4; i += 256) {
        int l = i >> 2, j = (i & 3) << 2;
        if (l >= LSEQ) {
            float4 z = make_float4(0.f, 0.f, 0.f, 0.f);
            *(float4*)&dS[l * 16 + j] = z;
            *(float4*)&bS[l * 16 + j] = z;
            *(float4*)&cS[l * 16 + j] = z;
            continue;
        }
        *(float4*)&bS[l * 16 + j] = *(const float4*)&dbcB[(size_t)l * 64 + DRANK + j];
        *(float4*)&cS[l * 16 + j] = *(const float4*)&dbcB[(size_t)l * 64 + DRANK + 16 + j];
        float4 acc = *(const float4*)&dtb[d0 + j];
#pragma unroll
        for (int kq = 0; kq < DRANK / 4; ++kq) {
            float4 r4 = *(const float4*)&dbcB[(size_t)l * 64 + kq * 4];
#pragma unroll
            for (int m = 0; m < 4; ++m) {
                float rv = (&r4.x)[m];
                float4 w4 = *(const float4*)&wS[(kq * 4 + m) * 16 + j];
                acc.x += rv * w4.x; acc.y += rv * w4.y;
                acc.z += rv * w4.z; acc.w += rv * w4.w;
            }
        }
        dS[l * 16 + j + 0] = sp_softplus(acc.x);
        dS[l * 16 + j + 1] = sp_softplus(acc.y);
        dS[l * 16 + j + 2] = sp_softplus(acc.z);
        dS[l * 16 + j + 3] = sp_softplus(acc.w);
    }
    const int n = tid & 15, dsub = tid >> 4;
    const int d = d0 + dsub;
    const float A  = -__expf(Alog[d * NSTATE + n]);
    const float Dv = Dp[d];

    // z register-prefetch (independent of scan; HBM latency hides under phase 2)
    ushort4 zreg[4];
#pragma unroll
    for (int it = 0; it < 4; ++it) {
        int i = tid + it * 256;
        if (i < LSEQ * 4) {
            int l = i >> 2, j = (i & 3) << 2;
            int t = b * LSEQ + l;
            zreg[it] = *(const ushort4*)&xzH[(size_t)t * (2 * DINNER) + DINNER + d0 + j];
        }
    }
    __syncthreads();

    // phase 2: batch-8 software-pipelined recurrence.
    // dsub columns are wave-private, so in-loop dS y-writes never race.
    float hn = 0.f;
    float dtc[8], uvc[8], Bnc[8], Cnc[8];
#pragma unroll
    for (int i = 0; i < 8; ++i) {
        int o = i * 16;
        dtc[i] = dS[o + dsub]; uvc[i] = uS[o + dsub];
        Bnc[i] = bS[o + n];    Cnc[i] = cS[o + n];
    }
    for (int lb = 0; lb < LPAD; lb += 8) {
        float dtN[8], uvN[8], BnN[8], CnN[8];
        if (lb + 8 < LPAD) {
#pragma unroll
            for (int i = 0; i < 8; ++i) {
                int o = (lb + 8 + i) * 16;
                dtN[i] = dS[o + dsub]; uvN[i] = uS[o + dsub];
                BnN[i] = bS[o + n];    CnN[i] = cS[o + n];
            }
        } else {
#pragma unroll
            for (int i = 0; i < 8; ++i) { dtN[i] = uvN[i] = BnN[i] = CnN[i] = 0.f; }
        }
        float a8[8], b8[8], p8[8];
#pragma unroll
        for (int i = 0; i < 8; ++i) {
            a8[i] = __expf(dtc[i] * A);
            b8[i] = dtc[i] * uvc[i] * Bnc[i];
        }
#pragma unroll
        for (int i = 0; i < 8; ++i) {
            hn = a8[i] * hn + b8[i];
            p8[i] = hn * Cnc[i];
        }
        row_sum16v<8>(p8);
#pragma unroll
        for (int i = 0; i < 8; ++i)
            if (n == 15) dS[(lb + i) * 16 + dsub] = p8[i] + uvc[i] * Dv;
#pragma unroll
        for (int i = 0; i < 8; ++i) {
            dtc[i] = dtN[i]; uvc[i] = uvN[i]; Bnc[i] = BnN[i]; Cnc[i] = CnN[i];
        }
    }
    __syncthreads();

    // phase 3: fused gate g = y * silu(z); z from registers, vectorized stores
#pragma unroll
    for (int it = 0; it < 4; ++it) {
        int i = tid + it * 256;
        if (i < LSEQ * 4) {
            int l = i >> 2, j = (i & 3) << 2;
            int t = b * LSEQ + l;
            union { ushort4 v; __half h[4]; } zu;
            zu.v = zreg[it];
            float4 g4 = make_float4(
                dS[l * 16 + j + 0] * sp_silu(__half2float(zu.h[0])),
                dS[l * 16 + j + 1] * sp_silu(__half2float(zu.h[1])),
                dS[l * 16 + j + 2] * sp_silu(__half2float(zu.h[2])),
                dS[l * 16 + j + 3] * sp_silu(__half2float(zu.h[3])));
            store_f16x4(gh, t, d0 + j, DINNER, g4);
        }
    }
}

// ------------- head stage 1: final residual reduce (8 rows only) + LN -> xr
__global__ __launch_bounds__(256) void k_head_ln(
    const float* __restrict__ part, const float* __restrict__ xtok,
    const float* __restrict__ lnw, const float* __restrict__ lnb,
    float* __restrict__ xr) {
    __shared__ float red[8];
    int b = blockIdx.x, tid = threadIdx.x;
    size_t base = ((size_t)(b * LSEQ + NPATCH)) * DMODEL;
    float v0 = xtok[base + tid], v1 = xtok[base + tid + 256];
#pragma unroll
    for (int k = 0; k < 2; ++k) {
        v0 += part[(size_t)k * (NTOK * DMODEL) + base + tid];
        v1 += part[(size_t)k * (NTOK * DMODEL) + base + tid + 256];
    }
    float2 t2 = block_reduce2(v0 + v1, v0 * v0 + v1 * v1, red);
    float mean = t2.x * (1.0f / DMODEL);
    float var  = t2.y * (1.0f / DMODEL) - mean * mean;
    float rstd = 1.0f / sqrtf(var + 1e-5f);
    xr[b * DMODEL + tid]       = (v0 - mean) * rstd * lnw[tid] + lnb[tid];
    xr[b * DMODEL + tid + 256] = (v1 - mean) * rstd * lnw[tid + 256] + lnb[tid + 256];
}

// ------------- head stage 2: k-split FC partials. grid (4, BATCH, 8)
__global__ __launch_bounds__(256) void k_head_fc(
    const float* __restrict__ xr, const float* __restrict__ hw,
    float* __restrict__ hpart) {
    __shared__ float xs[64];
    int tid = threadIdx.x;
    int c = blockIdx.x * 256 + tid;
    int b = blockIdx.y, ks = blockIdx.z;
    if (tid < 64) xs[tid] = xr[b * DMODEL + ks * 64 + tid];
    __syncthreads();
    if (c >= NCLS) return;
    float acc = 0.f;
#pragma unroll 8
    for (int k = 0; k < 64; ++k) acc += xs[k] * hw[(size_t)(ks * 64 + k) * NCLS + c];
    hpart[(size_t)(ks * BATCH + b) * NCLS + c] = acc;
}

// ------------- head stage 3: sum 8 partials + bias -> out
__global__ __launch_bounds__(256) void k_head_red(
    const float* __restrict__ hpart, const float* __restrict__ hb,
    float* __restrict__ out) {
    int i = blockIdx.x * 256 + threadIdx.x;
    if (i >= BATCH * NCLS) return;
    int b = i / NCLS, c = i % NCLS;
    float s = hb[c];
#pragma unroll
    for (int ks = 0; ks < 8; ++ks) s += hpart[(size_t)(ks * BATCH + b) * NCLS + c];
    out[i] = s;
}

extern "C" void kernel_launch(void* const* d_in, const int* in_sizes, int n_in,
                              void* d_out, int out_size, void* d_ws, size_t ws_size,
                              hipStream_t stream) {
    const float* img     = (const float*)d_in[0];
    const float* plnw    = (const float*)d_in[1];
    const float* plnb    = (const float*)d_in[2];
    const float* patch_w = (const float*)d_in[3];
    const float* patch_b = (const float*)d_in[4];
    const float* pos     = (const float*)d_in[5];
    const float* cls     = (const float*)d_in[6];
    const float* ln_w    = (const float*)d_in[7];
    const float* ln_b    = (const float*)d_in[8];
    const float* in_w    = (const float*)d_in[9];
    const float* conv_w  = (const float*)d_in[10];
    const float* conv_b  = (const float*)d_in[11];
    const float* xproj   = (const float*)d_in[12];
    const float* dt_w    = (const float*)d_in[13];
    const float* dt_b    = (const float*)d_in[14];
    const float* A_log   = (const float*)d_in[15];
    const float* Dp      = (const float*)d_in[16];
    const float* out_w   = (const float*)d_in[17];
    const float* hlnw    = (const float*)d_in[18];
    const float* hlnb    = (const float*)d_in[19];
    const float* head_w  = (const float*)d_in[20];
    const float* head_b  = (const float*)d_in[21];
    float* out = (float*)d_out;

    char* p = (char*)d_ws;
    auto alloc = [&](size_t bytes) { char* r = p; p += (bytes + 255) & ~(size_t)255; return r; };
    float* xtok = (float*)alloc((size_t)NTOK * DMODEL * 4);
    unsigned short* xzH = (unsigned short*)alloc((size_t)NTOK * 2 * DINNER * 2);
    float* dbc  = (float*)alloc((size_t)NTOK * 64 * 4);
    float* part = (float*)alloc((size_t)4 * NTOK * DMODEL * 4);
    float* xr   = (float*)alloc((size_t)BATCH * DMODEL * 4);
    float* hpart= (float*)alloc((size_t)8 * BATCH * NCLS * 4);
    char* ylnH = alloc((size_t)MPAD * DMODEL * 2);
    char* uH   = alloc((size_t)MPAD * DINNER * 2);
    char* gH   = alloc((size_t)MPAD * DINNER * 2);
    char* XpH  = alloc((size_t)MPAD * PDIM * 2);
    char* inTH  = alloc((size_t)NLAYER * 2 * DINNER * DMODEL * 2);
    char* outTH = alloc((size_t)NLAYER * DMODEL * DINNER * 2);
    char* patTH = alloc((size_t)DMODEL * PDIM * 2);
    char* xprTH = alloc((size_t)NLAYER * 128 * DINNER * 2);

    const size_t IN_T_B  = (size_t)2 * DINNER * DMODEL * 2;   // bytes/layer
    const size_t OUT_T_B = (size_t)DMODEL * DINNER * 2;
    const size_t XPR_T_B = (size_t)128 * DINNER * 2;

    // ---- one-time weight transpose + f16 cast (per call) ----
    k_wT<<<dim3(2 * DINNER / 32, DMODEL / 32, NLAYER), dim3(32, 8), 0, stream>>>(
        in_w, inTH, DMODEL, 2 * DINNER, (size_t)DMODEL * 2 * DINNER, IN_T_B);
    k_wT<<<dim3(DMODEL / 32, DINNER / 32, NLAYER), dim3(32, 8), 0, stream>>>(
        out_w, outTH, DINNER, DMODEL, (size_t)DINNER * DMODEL, OUT_T_B);
    k_wT<<<dim3(DMODEL / 32, PDIM / 32, 1), dim3(32, 8), 0, stream>>>(
        patch_w, patTH, PDIM, DMODEL, 0, 0);
    k_wT<<<dim3(128 / 32, DINNER / 32, NLAYER), dim3(32, 8), 0, stream>>>(
        xproj, xprTH, DINNER, 64, (size_t)DINNER * 64, XPR_T_B);

    // ---- patch embedding ----
    k_patch_ln<<<NPTOK, 256, 0, stream>>>(img, plnw, plnb, XpH);
    k_gemm<64, 128, false><<<dim3(4, 25, 4), 256, 0, stream>>>(
        XpH, patTH, part, nullptr, NPTOK, DMODEL, PDIM, 960, (long)NPTOK * DMODEL);
    k_patch_asm<<<(NTOK * DMODEL + 255) / 256, 256, 0, stream>>>(
        part, patch_b, cls, pos, xtok);

    // ---- mamba layers ----
    for (int i = 0; i < NLAYER; ++i) {
        if (i == 0) {
            k_ln<<<NTOK, 256, 0, stream>>>(xtok, ln_w, ln_b, ylnH);
        } else {
            k_red_ln<<<NTOK, 256, 0, stream>>>(part, xtok, ln_w + i * DMODEL,
                                               ln_b + i * DMODEL, ylnH);
        }
        k_gemm<64, 128, true><<<dim3(16, 25, 1), 256, 0, stream>>>(
            ylnH, inTH + i * IN_T_B, nullptr, xzH, NTOK, 2 * DINNER, DMODEL, DMODEL, 0);
        k_conv<<<(NTOK * (DINNER / 4) + 255) / 256, 256, 0, stream>>>(
            xzH, conv_w + (size_t)i * DINNER * 4, conv_b + (size_t)i * DINNER, uH);
        k_gemm<64, 64, false><<<dim3(1, 25, 4), 256, 0, stream>>>(
            uH, xprTH + i * XPR_T_B, part, nullptr, NTOK, 64, DINNER, 256, (long)NTOK * 64);
        k_reduce<4, false><<<(NTOK * 64 + 255) / 256, 256, 0, stream>>>(
            part, dbc, NTOK * 64, NTOK * 64);
        k_scan2<<<dim3(DINNER / 16, BATCH), 256, 0, stream>>>(
            uH, dbc, dt_w + (size_t)i * DRANK * DINNER, dt_b + (size_t)i * DINNER,
            A_log + (size_t)i * DINNER * NSTATE, Dp + (size_t)i * DINNER,
            xzH, gH);
        k_gemm<64, 128, false><<<dim3(4, 25, 2), 256, 0, stream>>>(
            gH, outTH + i * OUT_T_B, part, nullptr, NTOK, DMODEL, DINNER, 512,
            (long)NTOK * DMODEL);
    }

    // ---- head: residual reduce (8 rows) + LN, k-split FC, reduce ----
    k_head_ln<<<BATCH, 256, 0, stream>>>(part, xtok, hlnw, hlnb, xr);
    k_head_fc<<<dim3(4, BATCH, 8), 256, 0, stream>>>(xr, head_w, hpart);
    k_head_red<<<(BATCH * NCLS + 255) / 256, 256, 0, stream>>>(hpart, head_b, out);
}